// Round 8
// baseline (232.451 us; speedup 1.0000x reference)
//
#include <hip/hip_runtime.h>
#include <math.h>

namespace {
constexpr int   T_STEPS = 400;
constexpr int   HALF    = 200;           // T/2 — scan covers t = 1..200
constexpr int   NPIX    = 250 * 400;     // 100000
constexpr int   CHUNK   = 32;            // timesteps per load chunk
constexpr int   BLOCK   = 64;            // one wave per block: no LDS, no barriers
constexpr int   NBLK    = (NPIX + BLOCK - 1) / BLOCK;   // 1563
constexpr float U0 = 0.15f;
}

// order-preserving float <-> uint key. Both min and max accumulate via
// atomicMax (min as key(-val)) so a single 0x00 memset is the identity.
__device__ __forceinline__ unsigned fkey(float f) {
  const unsigned u = __float_as_uint(f);
  return (u & 0x80000000u) ? ~u : (u | 0x80000000u);
}
__device__ __forceinline__ float funkey(unsigned k) {
  const unsigned u = (k & 0x80000000u) ? (k ^ 0x80000000u) : ~k;
  return __uint_as_float(u);
}

// Exact math (R3-verbatim, 4x validated): n recurrence steps with interval d.
__device__ __forceinline__ void apply_segment(float& R, float& u, int d, int n) {
  const float dd = (float)d;
  const float eD = expf(-dd);              // exp(-isi / D), D = 1
  const float eF = expf(-(dd / 10.0f));    // exp(-isi / F), F = 10
  for (int k = 0; k < n; ++k) {
    const float Rn = 1.0f - (1.0f - R * (1.0f - u)) * eD;
    const float un = U0 + (u + 0.15f * (1.0f - u) - U0) * eF;
    R = Rn; u = un;
  }
}

__device__ __forceinline__ void proc_mask(unsigned mask, int t0, int& prev,
                                          float& R, float& u, bool& done) {
  if (done) return;
  while (mask) {
    const int i = __builtin_ctz(mask);
    mask &= mask - 1u;
    const int t = t0 + i;
    if (prev >= 0) {
      const int d = t - prev;
      // t <= HALF: segment (prev, t], endpoint updates only when isi==1
      // t >  HALF: segment clipped to (prev, HALF]
      const int n = (t <= HALF) ? ((d == 1) ? 1 : (d - 1)) : (HALF - prev);
      apply_segment(R, u, d, n);
    }
    prev = t;
    if (t >= HALF) { done = true; return; }
  }
}

// ONE fused kernel: column-walk read + recurrence -> keyed atomicMax pair ->
// balanced spin on arrival counter -> in-register normalize -> single store.
// Co-residency by construction: __launch_bounds__(64,2) => 8 blocks/CU
// capacity = 2048 >= NBLK=1563. Arrivals are balanced (identical work per
// wave), so the spin lasts only the arrival jitter — unlike R5's staggered
// 80 us convoy.
__global__ __launch_bounds__(BLOCK, 2) void stp_one(
    const float* __restrict__ spikes, float* __restrict__ img,
    unsigned* __restrict__ mm, unsigned* __restrict__ ctr) {
  const int  p      = blockIdx.x * BLOCK + threadIdx.x;
  const bool active = (p < NPIX);
  const float* __restrict__ sp = spikes + (active ? p : (NPIX - 1));

  bool  done = !active;
  int   prev = -1;
  float R = 1.0f, u = U0;

  auto loadc = [&](float (&buf)[CHUNK], int c) {
#pragma unroll
    for (int i = 0; i < CHUNK; ++i) {
      const unsigned idx = (unsigned)(c * CHUNK + i) * (unsigned)NPIX;
      buf[i] = sp[idx];
    }
  };
  auto maskof = [&](const float (&buf)[CHUNK]) -> unsigned {
    unsigned m = 0u;
#pragma unroll
    for (int i = 0; i < CHUNK; ++i) m |= (buf[i] > 0.0f) ? (1u << i) : 0u;
    return m;
  };

  // Software-pipelined double buffer; chunks 0..6 cover t in [0,224).
  float va[CHUNK], vb[CHUNK];
  loadc(va, 0);
  loadc(vb, 1);
  unsigned m;
  m = maskof(va); loadc(va, 2); proc_mask(m, 0 * CHUNK, prev, R, u, done);
  m = maskof(vb); loadc(vb, 3); proc_mask(m, 1 * CHUNK, prev, R, u, done);
  m = maskof(va); loadc(va, 4); proc_mask(m, 2 * CHUNK, prev, R, u, done);
  m = maskof(vb); loadc(vb, 5); proc_mask(m, 3 * CHUNK, prev, R, u, done);
  m = maskof(va); loadc(va, 6); proc_mask(m, 4 * CHUNK, prev, R, u, done);
  m = maskof(vb);               proc_mask(m, 5 * CHUNK, prev, R, u, done);
  m = maskof(va);               proc_mask(m, 6 * CHUNK, prev, R, u, done);

  // Rare tail (P ~ 64 * 2^-24 per wave); exact fallback on raw spikes.
  for (int c = 7; c <= (T_STEPS - 1) / CHUNK; ++c) {
    if (__all(done ? 1 : 0)) break;
    unsigned mt = 0u;
#pragma unroll
    for (int i = 0; i < CHUNK; ++i) {
      const int t = c * CHUNK + i;
      float v = 0.0f;
      if (t < T_STEPS) v = sp[(unsigned)t * (unsigned)NPIX];
      mt |= (v > 0.0f) ? (1u << i) : 0u;
    }
    proc_mask(mt, c * CHUNK, prev, R, u, done);
  }

  float val = 0.0f;
  if (active) {
    const float lu = logf((u - U0) / (10.0f - U0 + u * 0.85f));
    const float lR = logf((1.0f - R) / (1.0f - R * (1.0f - u)));
    val = (-1.0f / (10.0f * lu)) + (-1.0f / lR);
  }

  // wave min/max -> one keyed atomicMax pair per block -> release counter
  float vmin = active ? val : INFINITY;
  float vmax = active ? val : -INFINITY;
#pragma unroll
  for (int off = 32; off > 0; off >>= 1) {
    vmin = fminf(vmin, __shfl_down(vmin, off, 64));
    vmax = fmaxf(vmax, __shfl_down(vmax, off, 64));
  }
  if (threadIdx.x == 0) {
    atomicMax(&mm[0], fkey(-vmin));    // min slot: max of key(-val)
    atomicMax(&mm[1], fkey(vmax));     // max slot
    __hip_atomic_fetch_add(ctr, 1u, __ATOMIC_RELEASE,
                           __HIP_MEMORY_SCOPE_AGENT);
  }

  // balanced spin: all blocks resident; arrivals near-simultaneous
  while (__hip_atomic_load(ctr, __ATOMIC_ACQUIRE,
                           __HIP_MEMORY_SCOPE_AGENT) < (unsigned)NBLK) {
    __builtin_amdgcn_s_sleep(32);
  }

  const float mn = -funkey(__hip_atomic_load(&mm[0], __ATOMIC_RELAXED,
                                             __HIP_MEMORY_SCOPE_AGENT));
  const float mx =  funkey(__hip_atomic_load(&mm[1], __ATOMIC_RELAXED,
                                             __HIP_MEMORY_SCOPE_AGENT));
  if (active) {
    img[p] = (mx != mn) ? (val - mn) / (mx - mn) : val;
  }
}

extern "C" void kernel_launch(void* const* d_in, const int* in_sizes, int n_in,
                              void* d_out, int out_size, void* d_ws, size_t ws_size,
                              hipStream_t stream) {
  const float* spikes = (const float*)d_in[0];
  float*    out = (float*)d_out;
  unsigned* mm  = (unsigned*)d_ws;        // [0]=key(-min), [1]=key(max)
  unsigned* ctr = (unsigned*)d_ws + 2;    // [2]=arrival counter

  // single 12-byte zero-init: identity for both keyed maxes AND the counter
  hipMemsetAsync(mm, 0x00, 12, stream);

  hipLaunchKernelGGL(stp_one, dim3(NBLK), dim3(BLOCK), 0, stream,
                     spikes, out, mm, ctr);
}

// Round 9
// 204.532 us; speedup vs baseline: 1.1365x; 1.1365x over previous
//
#include <hip/hip_runtime.h>
#include <math.h>

namespace {
constexpr int   T_STEPS = 400;
constexpr int   HALF    = 200;           // T/2 — scan covers t = 1..200
constexpr int   NPIX    = 250 * 400;     // 100000
constexpr int   CHUNK   = 32;            // timesteps per load chunk
constexpr int   BLOCK   = 64;            // one wave per block: no LDS, no barriers
constexpr int   NBLK    = (NPIX + BLOCK - 1) / BLOCK;   // 1563
constexpr float U0 = 0.15f;
}

// order-preserving float <-> uint key. Both min and max accumulate via
// atomicMax (min as key(-val)) so zero-init is the identity for both.
__device__ __forceinline__ unsigned fkey(float f) {
  const unsigned u = __float_as_uint(f);
  return (u & 0x80000000u) ? ~u : (u | 0x80000000u);
}
__device__ __forceinline__ float funkey(unsigned k) {
  const unsigned u = (k & 0x80000000u) ? (k ^ 0x80000000u) : ~k;
  return __uint_as_float(u);
}

// Exact math (R3-verbatim, 5x validated): n recurrence steps with interval d.
__device__ __forceinline__ void apply_segment(float& R, float& u, int d, int n) {
  const float dd = (float)d;
  const float eD = expf(-dd);              // exp(-isi / D), D = 1
  const float eF = expf(-(dd / 10.0f));    // exp(-isi / F), F = 10
  for (int k = 0; k < n; ++k) {
    const float Rn = 1.0f - (1.0f - R * (1.0f - u)) * eD;
    const float un = U0 + (u + 0.15f * (1.0f - u) - U0) * eF;
    R = Rn; u = un;
  }
}

__device__ __forceinline__ void proc_mask(unsigned mask, int t0, int& prev,
                                          float& R, float& u, bool& done) {
  if (done) return;
  while (mask) {
    const int i = __builtin_ctz(mask);
    mask &= mask - 1u;
    const int t = t0 + i;
    if (prev >= 0) {
      const int d = t - prev;
      // t <= HALF: segment (prev, t], endpoint updates only when isi==1
      // t >  HALF: segment clipped to (prev, HALF]
      const int n = (t <= HALF) ? ((d == 1) ? 1 : (d - 1)) : (HALF - prev);
      apply_segment(R, u, d, n);
    }
    prev = t;
    if (t >= HALF) { done = true; return; }
  }
}

// ONE fused kernel. vs R8 (238 us): (1) arrival counter on its OWN cacheline
// (byte 256) — R8 had polls + atomicMax + counter on one 128B line, so the
// releases queued behind the poll storm (same-line convoy); (2) poll period
// 4x longer (s_sleep(127) ~ 3.4 us); (3) launch_bounds(64,1): occupancy is
// grid-limited (~6 blocks/CU < 8-cap), so min-waves=2 only capped VGPRs at
// 128 and killed the double buffer (VGPR_Count=60) — at 256-cap both
// 32-float buffers stay live.
__global__ __launch_bounds__(BLOCK, 1) void stp_one(
    const float* __restrict__ spikes, float* __restrict__ img,
    unsigned* __restrict__ mm, unsigned* __restrict__ ctr) {
  const int  p      = blockIdx.x * BLOCK + threadIdx.x;
  const bool active = (p < NPIX);
  const float* __restrict__ sp = spikes + (active ? p : (NPIX - 1));

  bool  done = !active;
  int   prev = -1;
  float R = 1.0f, u = U0;

  auto loadc = [&](float (&buf)[CHUNK], int c) {
#pragma unroll
    for (int i = 0; i < CHUNK; ++i) {
      const unsigned idx = (unsigned)(c * CHUNK + i) * (unsigned)NPIX;
      buf[i] = sp[idx];
    }
  };
  auto maskof = [&](const float (&buf)[CHUNK]) -> unsigned {
    unsigned m = 0u;
#pragma unroll
    for (int i = 0; i < CHUNK; ++i) m |= (buf[i] > 0.0f) ? (1u << i) : 0u;
    return m;
  };

  // Software-pipelined double buffer; chunks 0..6 cover t in [0,224).
  float va[CHUNK], vb[CHUNK];
  loadc(va, 0);
  loadc(vb, 1);
  unsigned m;
  m = maskof(va); loadc(va, 2); proc_mask(m, 0 * CHUNK, prev, R, u, done);
  m = maskof(vb); loadc(vb, 3); proc_mask(m, 1 * CHUNK, prev, R, u, done);
  m = maskof(va); loadc(va, 4); proc_mask(m, 2 * CHUNK, prev, R, u, done);
  m = maskof(vb); loadc(vb, 5); proc_mask(m, 3 * CHUNK, prev, R, u, done);
  m = maskof(va); loadc(va, 6); proc_mask(m, 4 * CHUNK, prev, R, u, done);
  m = maskof(vb);               proc_mask(m, 5 * CHUNK, prev, R, u, done);
  m = maskof(va);               proc_mask(m, 6 * CHUNK, prev, R, u, done);

  // Rare tail (P ~ 64 * 2^-24 per wave); exact fallback on raw spikes.
  for (int c = 7; c <= (T_STEPS - 1) / CHUNK; ++c) {
    if (__all(done ? 1 : 0)) break;
    unsigned mt = 0u;
#pragma unroll
    for (int i = 0; i < CHUNK; ++i) {
      const int t = c * CHUNK + i;
      float v = 0.0f;
      if (t < T_STEPS) v = sp[(unsigned)t * (unsigned)NPIX];
      mt |= (v > 0.0f) ? (1u << i) : 0u;
    }
    proc_mask(mt, c * CHUNK, prev, R, u, done);
  }

  float val = 0.0f;
  if (active) {
    const float lu = logf((u - U0) / (10.0f - U0 + u * 0.85f));
    const float lR = logf((1.0f - R) / (1.0f - R * (1.0f - u)));
    val = (-1.0f / (10.0f * lu)) + (-1.0f / lR);
  }

  // wave min/max -> one keyed atomicMax pair per block -> release counter
  float vmin = active ? val : INFINITY;
  float vmax = active ? val : -INFINITY;
#pragma unroll
  for (int off = 32; off > 0; off >>= 1) {
    vmin = fminf(vmin, __shfl_down(vmin, off, 64));
    vmax = fmaxf(vmax, __shfl_down(vmax, off, 64));
  }
  if (threadIdx.x == 0) {
    atomicMax(&mm[0], fkey(-vmin));    // min slot: max of key(-val)
    atomicMax(&mm[1], fkey(vmax));     // max slot
    __hip_atomic_fetch_add(ctr, 1u, __ATOMIC_RELEASE,
                           __HIP_MEMORY_SCOPE_AGENT);
  }

  // low-pressure spin: counter on its own cacheline, ~3.4 us poll period
  while (__hip_atomic_load(ctr, __ATOMIC_ACQUIRE,
                           __HIP_MEMORY_SCOPE_AGENT) < (unsigned)NBLK) {
    __builtin_amdgcn_s_sleep(127);
  }

  const float mn = -funkey(__hip_atomic_load(&mm[0], __ATOMIC_RELAXED,
                                             __HIP_MEMORY_SCOPE_AGENT));
  const float mx =  funkey(__hip_atomic_load(&mm[1], __ATOMIC_RELAXED,
                                             __HIP_MEMORY_SCOPE_AGENT));
  if (active) {
    img[p] = (mx != mn) ? (val - mn) / (mx - mn) : val;
  }
}

extern "C" void kernel_launch(void* const* d_in, const int* in_sizes, int n_in,
                              void* d_out, int out_size, void* d_ws, size_t ws_size,
                              hipStream_t stream) {
  const float* spikes = (const float*)d_in[0];
  float*    out = (float*)d_out;
  unsigned* ws  = (unsigned*)d_ws;
  unsigned* mm  = ws;                     // [0]=key(-min), [1]=key(max)  (line A)
  unsigned* ctr = ws + 64;                // byte offset 256 (its own line B)

  // zero-init lines A+B in one node: identity for keyed maxes AND counter
  hipMemsetAsync(ws, 0x00, 264, stream);

  hipLaunchKernelGGL(stp_one, dim3(NBLK), dim3(BLOCK), 0, stream,
                     spikes, out, mm, ctr);
}